// Round 13
// baseline (410.784 us; speedup 1.0000x reference)
//
#include <hip/hip_runtime.h>
#include <hip/hip_bf16.h>
#include <hip/hip_fp16.h>

#define NB 8192
#define D_IN 3200
#define D_H 128
#define NE 5

typedef _Float16 f16x8 __attribute__((ext_vector_type(8)));
typedef _Float16 f16x4 __attribute__((ext_vector_type(4)));
typedef float f32x4 __attribute__((ext_vector_type(4)));

// async global->LDS, 16B per lane; global addr may be per-lane, LDS base wave-uniform
__device__ __forceinline__ void gload16(const _Float16* g, _Float16* l) {
    __builtin_amdgcn_global_load_lds(
        (const __attribute__((address_space(1))) void*)g,
        (__attribute__((address_space(3))) void*)l, 16, 0, 0);
}

// ---------------- kernel 0: gwC transpose + cnt zero (must precede k_feat: k_feat reads gwC)
__global__ __launch_bounds__(256) void k_gwprep(const float* __restrict__ gw,
                                                float* __restrict__ gwC,
                                                int* __restrict__ cnt) {
    int i = blockIdx.x * 256 + threadIdx.x;
    if (i < 16000) {
        int e = i / 3200, rem = i - e * 3200;
        int o = rem >> 5, co = rem & 31;
        gwC[i] = gw[(co * 100 + o) * 5 + e];
    }
    if (blockIdx.x == 0 && threadIdx.x < NE) cnt[threadIdx.x] = 0;
}

// ---------------- kernel 1: blocks 0-519 = wT/e2T transpose prep; blocks 520+ = conv path.
#define PCL_S 24
__global__ __launch_bounds__(256, 3) void k_feat(
    const float* __restrict__ x, const float* __restrict__ c1w, const float* __restrict__ c1b,
    const float* __restrict__ c2w, const float* __restrict__ c2b,
    const float* __restrict__ gwC, const float* __restrict__ gb,
    const float* __restrict__ e1w, _Float16* __restrict__ wT,
    const float* __restrict__ e2w, _Float16* __restrict__ e2T,
    _Float16* __restrict__ h16, float* __restrict__ wfull)
{
    __shared__ union {
        struct {
            __align__(16) float xs[784];
            __align__(16) float c1wsP[448];
            __align__(16) _Float16 b2h[5120];
            __align__(16) _Float16 b2l[5120];
            __align__(16) _Float16 pclh[144 * PCL_S];
            __align__(16) _Float16 pcll[144 * PCL_S];
            float red[32];
        } f;
        float tile[64 * 65];   // prep transpose scratch (16.6 KB, overlaid)
    } S;
    int bid = blockIdx.x;
    int t = threadIdx.x;

    if (bid < 520) {               // ---- prep path
        if (bid < 500) {           // e1_w [5][3200][128] -> f16 T [5][128][3200]
            int e = bid / 100, rem = bid - e * 100;
            int k0 = (rem >> 1) * 64, n0 = (rem & 1) * 64;
            const float* src = e1w + (size_t)e * D_IN * D_H;
            _Float16* dst = wT + (size_t)e * D_H * D_IN;
            for (int i = 0; i < 16; ++i) {
                int idx = t + i * 256;
                int kr = idx >> 6, nc = idx & 63;
                S.tile[kr * 65 + nc] = src[(size_t)(k0 + kr) * D_H + n0 + nc];
            }
            __syncthreads();
            for (int i = 0; i < 16; ++i) {
                int idx = t + i * 256;
                int nr = idx >> 6, kc = idx & 63;
                dst[(size_t)(n0 + nr) * D_IN + k0 + kc] = (_Float16)S.tile[kc * 65 + nr];
            }
        } else {                   // e2_w [5][128][128] -> f16 T (n,k)
            int idx2 = bid - 500;
            int e = idx2 >> 2, rem = idx2 & 3;
            int k0 = (rem >> 1) * 64, n0 = (rem & 1) * 64;
            const float* src = e2w + (size_t)e * D_H * D_H;
            _Float16* dst = e2T + (size_t)e * D_H * D_H;
            for (int i = 0; i < 16; ++i) {
                int idx = t + i * 256;
                int kr = idx >> 6, nc = idx & 63;
                S.tile[kr * 65 + nc] = src[(size_t)(k0 + kr) * D_H + n0 + nc];
            }
            __syncthreads();
            for (int i = 0; i < 16; ++i) {
                int idx = t + i * 256;
                int nr = idx >> 6, kc = idx & 63;
                dst[(size_t)(n0 + nr) * D_H + k0 + kc] = (_Float16)S.tile[kc * 65 + nr];
            }
        }
        return;
    }

    int b = bid - 520;             // ---- conv path (proven structure, frozen)
    for (int i = t; i < 784; i += 256) S.f.xs[i] = x[(size_t)b * 784 + i];
    for (int i = t; i < 400; i += 256) {
        int c = i / 25, q = i - c * 25;
        S.f.c1wsP[c * 28 + q] = c1w[i];
    }
    for (int i = t; i < 5120; i += 256) {
        int co = i / 160, k = i - co * 160;
        int s = k >> 4, ci = k & 15;
        float v = (s == 9) ? 0.f : c2w[(co * 16 + ci) * 9 + s];
        _Float16 vh = (_Float16)v;
        S.f.b2h[i] = vh;
        S.f.b2l[i] = (_Float16)(v - (float)vh);
    }
    __syncthreads();

    // conv1 + 2x2 maxpool -> pcl channel-last (hi/lo f16)
    {
        int c = t >> 4;
        int tile = t & 15;
        int tr = tile >> 2, tc = tile & 3;
        float w1r[25];
        #pragma unroll
        for (int q = 0; q < 6; ++q) {
            float4 v4 = *(const float4*)&S.f.c1wsP[c * 28 + q * 4];
            w1r[q * 4 + 0] = v4.x; w1r[q * 4 + 1] = v4.y;
            w1r[q * 4 + 2] = v4.z; w1r[q * 4 + 3] = v4.w;
        }
        w1r[24] = S.f.c1wsP[c * 28 + 24];
        float bias1 = c1b[c];
        float win[5][10];
        float pacc[3][3];
        #pragma unroll
        for (int i = 0; i < 3; ++i)
            #pragma unroll
            for (int j = 0; j < 3; ++j) pacc[i][j] = 0.f;
        int r0 = 6 * tr, col0 = 6 * tc;
        #pragma unroll
        for (int cr = 0; cr < 6; ++cr) {
            if (cr == 0) {
                #pragma unroll
                for (int rr = 0; rr < 5; ++rr)
                    #pragma unroll
                    for (int m = 0; m < 5; ++m) {
                        float2 v = *(const float2*)&S.f.xs[(r0 + rr) * 28 + col0 + 2 * m];
                        win[rr][2 * m] = v.x; win[rr][2 * m + 1] = v.y;
                    }
            } else {
                int dstr = (cr + 4) % 5;
                #pragma unroll
                for (int m = 0; m < 5; ++m) {
                    float2 v = *(const float2*)&S.f.xs[(r0 + cr + 4) * 28 + col0 + 2 * m];
                    win[dstr][2 * m] = v.x; win[dstr][2 * m + 1] = v.y;
                }
            }
            #pragma unroll
            for (int oc = 0; oc < 6; ++oc) {
                float s = bias1;
                #pragma unroll
                for (int u = 0; u < 5; ++u)
                    #pragma unroll
                    for (int v = 0; v < 5; ++v)
                        s += win[(cr + u) % 5][oc + v] * w1r[u * 5 + v];
                s = fmaxf(s, 0.f);
                pacc[cr >> 1][oc >> 1] = fmaxf(pacc[cr >> 1][oc >> 1], s);
            }
        }
        #pragma unroll
        for (int i = 0; i < 3; ++i)
            #pragma unroll
            for (int j = 0; j < 3; ++j) {
                int pos = (3 * tr + i) * 12 + (3 * tc + j);
                float v = pacc[i][j];
                _Float16 vh = (_Float16)v;
                S.f.pclh[pos * PCL_S + c] = vh;
                S.f.pcll[pos * PCL_S + c] = (_Float16)(v - (float)vh);
            }
    }
    __syncthreads();

    // conv2 MFMA: wave fixed nt (B frags in regs), mt strided
    float part[5] = {0, 0, 0, 0, 0};
    int lane = t & 63, wv = t >> 6;
    int quad = lane >> 4, l16 = lane & 15;
    int quadh = quad >> 1, quadl = quad & 1;
    const int offA[5] = {0, 2, 13, 24, 26};
    const int offB[5] = {1, 12, 14, 25, 0};
    {
        int nt = wv & 1;
        int co = nt * 16 + l16;
        f16x8 bh[5], bl[5];
        #pragma unroll
        for (int kc = 0; kc < 5; ++kc) {
            bh[kc] = *(const f16x8*)&S.f.b2h[co * 160 + kc * 32 + quad * 8];
            bl[kc] = *(const f16x8*)&S.f.b2l[co * 160 + kc * 32 + quad * 8];
        }
        float bco = c2b[co];
        for (int mt = wv >> 1; mt < 7; mt += 2) {
            int o_a = mt * 16 + l16;
            int o_cl = o_a < 100 ? o_a : 99;
            int pb = (o_cl / 10) * 12 + (o_cl % 10);
            f32x4 acc = (f32x4){0.f, 0.f, 0.f, 0.f};
            #pragma unroll
            for (int kc = 0; kc < 5; ++kc) {
                int off = quadh ? offB[kc] : offA[kc];
                f16x8 ah = *(const f16x8*)&S.f.pclh[(pb + off) * PCL_S + quadl * 8];
                f16x8 al = *(const f16x8*)&S.f.pcll[(pb + off) * PCL_S + quadl * 8];
                acc = __builtin_amdgcn_mfma_f32_16x16x32_f16(ah, bh[kc], acc, 0, 0, 0);
                acc = __builtin_amdgcn_mfma_f32_16x16x32_f16(ah, bl[kc], acc, 0, 0, 0);
                acc = __builtin_amdgcn_mfma_f32_16x16x32_f16(al, bh[kc], acc, 0, 0, 0);
            }
            if (mt < 6 || quad == 0) {
                int o0 = mt * 16 + quad * 4;
                f16x4 st;
                #pragma unroll
                for (int r = 0; r < 4; ++r) {
                    float hv = fmaxf(acc[r] + bco, 0.f);
                    st[r] = (_Float16)hv;
                    #pragma unroll
                    for (int e = 0; e < 5; ++e)
                        part[e] += hv * gwC[e * 3200 + (o0 + r) * 32 + co];
                }
                *(f16x4*)&h16[(size_t)b * D_IN + co * 100 + o0] = st;
            }
        }
    }

    // gate reduce: softmax, top-3 renormalized
    #pragma unroll
    for (int e = 0; e < 5; ++e) {
        float v = part[e];
        for (int off = 32; off > 0; off >>= 1) v += __shfl_down(v, off, 64);
        if (lane == 0) S.f.red[wv * 8 + e] = v;
    }
    __syncthreads();
    if (t == 0) {
        float lg[5], p[5];
        float mx = -1e30f;
        for (int e = 0; e < 5; ++e) {
            lg[e] = S.f.red[e] + S.f.red[8 + e] + S.f.red[16 + e] + S.f.red[24 + e] + gb[e];
            mx = fmaxf(mx, lg[e]);
        }
        float sum = 0.f;
        for (int e = 0; e < 5; ++e) { p[e] = expf(lg[e] - mx); sum += p[e]; }
        for (int e = 0; e < 5; ++e) p[e] /= sum;
        bool used[5] = {false, false, false, false, false};
        float out5[5] = {0, 0, 0, 0, 0};
        int ti[3]; float tv[3]; float tsum = 0.f;
        for (int jj = 0; jj < 3; ++jj) {
            int best = 0; float bv = -1.f;
            for (int e = 0; e < 5; ++e)
                if (!used[e] && p[e] > bv) { bv = p[e]; best = e; }
            used[best] = true; ti[jj] = best; tv[jj] = bv; tsum += bv;
        }
        for (int jj = 0; jj < 3; ++jj) out5[ti[jj]] = tv[jj] / tsum;
        for (int e = 0; e < 5; ++e) wfull[b * 5 + e] = out5[e];
    }
}

// ---------------- kernel 1b: token compaction — wave-aggregated (640 atomics total)
__global__ __launch_bounds__(256) void k_compact(
    const float* __restrict__ wfull, int* __restrict__ cnt, int* __restrict__ lists)
{
    int tok = blockIdx.x * 256 + threadIdx.x;
    int lane = threadIdx.x & 63;
    float w[5];
    #pragma unroll
    for (int e = 0; e < 5; ++e) w[e] = wfull[(size_t)tok * 5 + e];
    #pragma unroll
    for (int e = 0; e < 5; ++e) {
        bool sel = w[e] > 0.f;
        unsigned long long mask = __ballot(sel);
        int leader = __ffsll((long long)mask) - 1;
        int base = 0;
        if (lane == leader) base = atomicAdd(&cnt[e], __popcll(mask));
        base = __shfl(base, leader, 64);
        if (sel) {
            int pos = base + __popcll(mask & ((1ull << lane) - 1ull));
            lists[e * NB + pos] = tok;
        }
    }
}

// ---------------- kernel 2: experts on compacted lists, 64-row M-tiles (R11 proven),
// BK=128 per barrier pair (4 chunks staged per drain: 25 K-iterations, was 50).
// Grid-limited (~387 active blocks ~1.5/CU) so the 2-blocks/CU LDS cap is harmless.
#define H1S 136
union SLds {
    struct { _Float16 As[4][2048]; _Float16 Bs[4][4096]; } p1;  // 48 KB staging
    _Float16 e2ws[128 * H1S];                                   // 34.8 KB e2 weights
    float smws[1280];                                           // 5 KB head weights
};

__global__ __launch_bounds__(256, 2) void k_e1e2(
    const _Float16* __restrict__ h16, const _Float16* __restrict__ wT,
    const _Float16* __restrict__ e2T,
    const float* __restrict__ e1b, const float* __restrict__ e2b,
    const float* __restrict__ smw,
    const float* __restrict__ wfull, const int* __restrict__ cnt,
    const int* __restrict__ lists, float* __restrict__ logits)
{
    __shared__ SLds u;
    __shared__ __align__(16) _Float16 h1s[64 * H1S];
    __shared__ float wfl[64];
    __shared__ int rows[64];
    int bid = blockIdx.x;
    int e = bid >> 7;            // expert-major: one B matrix hot per L2 at a time
    int mt = bid & 127;
    int cnt_e = cnt[e];
    int m0 = mt * 64;
    if (m0 >= cnt_e) return;     // inactive tile, uniform exit
    int t = threadIdx.x;
    int lane = t & 63, wv = t >> 6;
    int waveM = wv >> 1, waveN = wv & 1;
    int quad = lane >> 4, l16 = lane & 15;
    if (t < 64) {
        int r = m0 + t;
        int row = (r < cnt_e) ? lists[e * NB + r] : lists[e * NB];  // dup row for tail
        rows[t] = row;
        wfl[t] = (r < cnt_e) ? wfull[(size_t)row * 5 + e] : 0.f;    // tail w=0
    }
    __syncthreads();

    const _Float16* bbase = wT + (size_t)e * (D_H * D_IN);
    int srow = t >> 2;
    int scol = (t & 3) * 8;
    const _Float16* aptr = h16 + (size_t)rows[srow] * D_IN + scol;
    const _Float16* bptr0 = bbase + (size_t)srow * D_IN + scol;
    const _Float16* bptr1 = bbase + (size_t)(64 + srow) * D_IN + scol;
    f32x4 acc[2][4];
    #pragma unroll
    for (int i = 0; i < 2; ++i)
        #pragma unroll
        for (int j = 0; j < 4; ++j) acc[i][j] = (f32x4){0.f, 0.f, 0.f, 0.f};

    for (int k0 = 0; k0 < D_IN; k0 += 128) {   // 25 iterations
        #pragma unroll
        for (int c = 0; c < 4; ++c) {
            gload16(aptr + k0 + c * 32,  u.p1.As[c] + wv * 512);
            gload16(bptr0 + k0 + c * 32, u.p1.Bs[c] + wv * 512);
            gload16(bptr1 + k0 + c * 32, u.p1.Bs[c] + 2048 + wv * 512);
        }
        __syncthreads();   // single drain for all four 32-chunks
        #pragma unroll
        for (int ch = 0; ch < 4; ++ch) {
            f16x8 af[2], bf[4];
            #pragma unroll
            for (int ms = 0; ms < 2; ++ms)
                af[ms] = *(const f16x8*)&u.p1.As[ch][(waveM * 32 + ms * 16 + l16) * 32 + quad * 8];
            #pragma unroll
            for (int ns = 0; ns < 4; ++ns)
                bf[ns] = *(const f16x8*)&u.p1.Bs[ch][(waveN * 64 + ns * 16 + l16) * 32 + quad * 8];
            #pragma unroll
            for (int ms = 0; ms < 2; ++ms)
                #pragma unroll
                for (int ns = 0; ns < 4; ++ns)
                    acc[ms][ns] = __builtin_amdgcn_mfma_f32_16x16x32_f16(af[ms], bf[ns], acc[ms][ns], 0, 0, 0);
        }
        __syncthreads();
    }

    // h1 = tanh(acc + b1) -> h1s
    #pragma unroll
    for (int ms = 0; ms < 2; ++ms) {
        int rbase = waveM * 32 + ms * 16 + quad * 4;
        #pragma unroll
        for (int ns = 0; ns < 4; ++ns) {
            int n = waveN * 64 + ns * 16 + l16;
            float bias = e1b[e * D_H + n];
            #pragma unroll
            for (int r = 0; r < 4; ++r)
                h1s[(rbase + r) * H1S + n] = (_Float16)tanhf(acc[ms][ns][r] + bias);
        }
    }
    __syncthreads();   // h1s visible; staging dead -> reuse as e2ws

    {
        int rr = t >> 1, cc = (t & 1) * 64;
        const _Float16* src = e2T + (size_t)e * (D_H * D_H) + (size_t)rr * D_H + cc;
        #pragma unroll
        for (int i = 0; i < 8; ++i)
            *(uint4*)&u.e2ws[rr * H1S + cc + i * 8] = *(const uint4*)(src + i * 8);
    }
    __syncthreads();

    f32x4 acc2[2][4];
    #pragma unroll
    for (int i = 0; i < 2; ++i)
        #pragma unroll
        for (int j = 0; j < 4; ++j) acc2[i][j] = (f32x4){0.f, 0.f, 0.f, 0.f};
    #pragma unroll
    for (int kc = 0; kc < 4; ++kc) {
        f16x8 a2[2], b2[4];
        #pragma unroll
        for (int ms = 0; ms < 2; ++ms)
            a2[ms] = *(const f16x8*)&h1s[(waveM * 32 + ms * 16 + l16) * H1S + kc * 32 + quad * 8];
        #pragma unroll
        for (int ns = 0; ns < 4; ++ns)
            b2[ns] = *(const f16x8*)&u.e2ws[(waveN * 64 + ns * 16 + l16) * H1S + kc * 32 + quad * 8];
        #pragma unroll
        for (int ms = 0; ms < 2; ++ms)
            #pragma unroll
            for (int ns = 0; ns < 4; ++ns)
                acc2[ms][ns] = __builtin_amdgcn_mfma_f32_16x16x32_f16(a2[ms], b2[ns], acc2[ms][ns], 0, 0, 0);
    }
    __syncthreads();   // all h1s/e2ws reads done -> safe to overwrite both

    // wh2 = w * tanh(acc2 + b2) -> h1s (f16); stage smw -> u.smws
    for (int i = t; i < 1280; i += 256) u.smws[i] = smw[i];
    #pragma unroll
    for (int ms = 0; ms < 2; ++ms) {
        int rbase = waveM * 32 + ms * 16 + quad * 4;
        #pragma unroll
        for (int ns = 0; ns < 4; ++ns) {
            int n = waveN * 64 + ns * 16 + l16;
            float bias = e2b[e * D_H + n];
            #pragma unroll
            for (int r = 0; r < 4; ++r) {
                int lrow = rbase + r;
                h1s[lrow * H1S + n] = (_Float16)(wfl[lrow] * tanhf(acc2[ms][ns][r] + bias));
            }
        }
    }
    __syncthreads();

    // in-block head GEMM: partial_logits[64][10] = wh2 @ smw; atomic combine
    for (int i = t; i < 640; i += 256) {
        int row = i / 10, c = i - (i / 10) * 10;
        float s = 0.f;
        #pragma unroll 8
        for (int k = 0; k < 128; ++k)
            s += (float)h1s[row * H1S + k] * u.smws[k * 10 + c];
        unsafeAtomicAdd(&logits[(size_t)rows[row] * 10 + c], s);
    }
}

// ---------------- kernel 3: softmax over logits (+smb) -> out
__global__ __launch_bounds__(256) void k_smax(
    const float* __restrict__ logits, const float* __restrict__ smb,
    float* __restrict__ out)
{
    int r = blockIdx.x * 256 + threadIdx.x;
    float lg[10];
    float mx = -1e30f;
    #pragma unroll
    for (int c = 0; c < 10; ++c) {
        lg[c] = logits[(size_t)r * 10 + c] + smb[c];
        mx = fmaxf(mx, lg[c]);
    }
    float s = 0.f;
    #pragma unroll
    for (int c = 0; c < 10; ++c) { lg[c] = expf(lg[c] - mx); s += lg[c]; }
    float inv = 1.f / s;
    #pragma unroll
    for (int c = 0; c < 10; ++c) out[(size_t)r * 10 + c] = lg[c] * inv;
}

extern "C" void kernel_launch(void* const* d_in, const int* in_sizes, int n_in,
                              void* d_out, int out_size, void* d_ws, size_t ws_size,
                              hipStream_t stream)
{
    const float* x   = (const float*)d_in[0];
    const float* c1w = (const float*)d_in[1];
    const float* c1b = (const float*)d_in[2];
    const float* c2w = (const float*)d_in[3];
    const float* c2b = (const float*)d_in[4];
    const float* gw  = (const float*)d_in[5];
    const float* gb  = (const float*)d_in[6];
    const float* e1w = (const float*)d_in[7];
    const float* e1b = (const float*)d_in[8];
    const float* e2w = (const float*)d_in[9];
    const float* e2b = (const float*)d_in[10];
    const float* smw = (const float*)d_in[11];
    const float* smb = (const float*)d_in[12];
    float* out = (float*)d_out;

    char* ws = (char*)d_ws;
    size_t off = 0;
    auto alloc = [&](size_t bytes) {
        void* p = ws + off;
        off += (bytes + 255) & ~(size_t)255;
        return p;
    };
    _Float16* h16 = (_Float16*)alloc((size_t)NB * D_IN * 2);          // 52.4 MB
    _Float16* wT  = (_Float16*)alloc((size_t)NE * D_H * D_IN * 2);    // 4.1 MB
    _Float16* e2T = (_Float16*)alloc((size_t)NE * D_H * D_H * 2);     // 0.16 MB
    float* wfull  = (float*)alloc((size_t)NB * NE * 4);               // 0.16 MB
    float* logits = (float*)alloc((size_t)NB * 10 * 4);               // 0.33 MB
    float* gwC    = (float*)alloc((size_t)NE * D_IN * 4);             // 64 KB
    int* cnt      = (int*)alloc(NE * 4);
    int* lists    = (int*)alloc((size_t)NE * NB * 4);                 // 160 KB

    hipMemsetAsync(logits, 0, (size_t)NB * 10 * 4, stream);
    k_gwprep<<<dim3(63), 256, 0, stream>>>(gw, gwC, cnt);
    k_feat<<<dim3(520 + NB), 256, 0, stream>>>(x, c1w, c1b, c2w, c2b, gwC, gb,
                                               e1w, wT, e2w, e2T, h16, wfull);
    k_compact<<<dim3(NB / 256), 256, 0, stream>>>(wfull, cnt, lists);
    k_e1e2<<<dim3(128 * NE), 256, 0, stream>>>(h16, wT, e2T, e1b, e2b, smw,
                                               wfull, cnt, lists, logits);
    k_smax<<<dim3(NB / 256), 256, 0, stream>>>(logits, smb, out);
}

// Round 14
// 311.801 us; speedup vs baseline: 1.3175x; 1.3175x over previous
//
#include <hip/hip_runtime.h>
#include <hip/hip_bf16.h>
#include <hip/hip_fp16.h>

#define NB 8192
#define D_IN 3200
#define D_H 128
#define NE 5

typedef _Float16 f16x8 __attribute__((ext_vector_type(8)));
typedef _Float16 f16x4 __attribute__((ext_vector_type(4)));
typedef float f32x4 __attribute__((ext_vector_type(4)));

// async global->LDS, 16B per lane; global addr may be per-lane, LDS base wave-uniform
__device__ __forceinline__ void gload16(const _Float16* g, _Float16* l) {
    __builtin_amdgcn_global_load_lds(
        (const __attribute__((address_space(1))) void*)g,
        (__attribute__((address_space(3))) void*)l, 16, 0, 0);
}

// ---------------- kernel 0: gwC transpose + cnt zero (must precede k_feat: k_feat reads gwC)
__global__ __launch_bounds__(256) void k_gwprep(const float* __restrict__ gw,
                                                float* __restrict__ gwC,
                                                int* __restrict__ cnt) {
    int i = blockIdx.x * 256 + threadIdx.x;
    if (i < 16000) {
        int e = i / 3200, rem = i - e * 3200;
        int o = rem >> 5, co = rem & 31;
        gwC[i] = gw[(co * 100 + o) * 5 + e];
    }
    if (blockIdx.x == 0 && threadIdx.x < NE) cnt[threadIdx.x] = 0;
}

// ---------------- kernel 1: blocks 0-519 = wT/e2T transpose prep; blocks 520+ = conv path.
#define PCL_S 24
__global__ __launch_bounds__(256, 3) void k_feat(
    const float* __restrict__ x, const float* __restrict__ c1w, const float* __restrict__ c1b,
    const float* __restrict__ c2w, const float* __restrict__ c2b,
    const float* __restrict__ gwC, const float* __restrict__ gb,
    const float* __restrict__ e1w, _Float16* __restrict__ wT,
    const float* __restrict__ e2w, _Float16* __restrict__ e2T,
    _Float16* __restrict__ h16, float* __restrict__ wfull)
{
    __shared__ union {
        struct {
            __align__(16) float xs[784];
            __align__(16) float c1wsP[448];
            __align__(16) _Float16 b2h[5120];
            __align__(16) _Float16 b2l[5120];
            __align__(16) _Float16 pclh[144 * PCL_S];
            __align__(16) _Float16 pcll[144 * PCL_S];
            float red[32];
        } f;
        float tile[64 * 65];   // prep transpose scratch (16.6 KB, overlaid)
    } S;
    int bid = blockIdx.x;
    int t = threadIdx.x;

    if (bid < 520) {               // ---- prep path
        if (bid < 500) {           // e1_w [5][3200][128] -> f16 T [5][128][3200]
            int e = bid / 100, rem = bid - e * 100;
            int k0 = (rem >> 1) * 64, n0 = (rem & 1) * 64;
            const float* src = e1w + (size_t)e * D_IN * D_H;
            _Float16* dst = wT + (size_t)e * D_H * D_IN;
            for (int i = 0; i < 16; ++i) {
                int idx = t + i * 256;
                int kr = idx >> 6, nc = idx & 63;
                S.tile[kr * 65 + nc] = src[(size_t)(k0 + kr) * D_H + n0 + nc];
            }
            __syncthreads();
            for (int i = 0; i < 16; ++i) {
                int idx = t + i * 256;
                int nr = idx >> 6, kc = idx & 63;
                dst[(size_t)(n0 + nr) * D_IN + k0 + kc] = (_Float16)S.tile[kc * 65 + nr];
            }
        } else {                   // e2_w [5][128][128] -> f16 T (n,k)
            int idx2 = bid - 500;
            int e = idx2 >> 2, rem = idx2 & 3;
            int k0 = (rem >> 1) * 64, n0 = (rem & 1) * 64;
            const float* src = e2w + (size_t)e * D_H * D_H;
            _Float16* dst = e2T + (size_t)e * D_H * D_H;
            for (int i = 0; i < 16; ++i) {
                int idx = t + i * 256;
                int kr = idx >> 6, nc = idx & 63;
                S.tile[kr * 65 + nc] = src[(size_t)(k0 + kr) * D_H + n0 + nc];
            }
            __syncthreads();
            for (int i = 0; i < 16; ++i) {
                int idx = t + i * 256;
                int nr = idx >> 6, kc = idx & 63;
                dst[(size_t)(n0 + nr) * D_H + k0 + kc] = (_Float16)S.tile[kc * 65 + nr];
            }
        }
        return;
    }

    int b = bid - 520;             // ---- conv path (proven structure, frozen)
    for (int i = t; i < 784; i += 256) S.f.xs[i] = x[(size_t)b * 784 + i];
    for (int i = t; i < 400; i += 256) {
        int c = i / 25, q = i - c * 25;
        S.f.c1wsP[c * 28 + q] = c1w[i];
    }
    for (int i = t; i < 5120; i += 256) {
        int co = i / 160, k = i - co * 160;
        int s = k >> 4, ci = k & 15;
        float v = (s == 9) ? 0.f : c2w[(co * 16 + ci) * 9 + s];
        _Float16 vh = (_Float16)v;
        S.f.b2h[i] = vh;
        S.f.b2l[i] = (_Float16)(v - (float)vh);
    }
    __syncthreads();

    // conv1 + 2x2 maxpool -> pcl channel-last (hi/lo f16)
    {
        int c = t >> 4;
        int tile = t & 15;
        int tr = tile >> 2, tc = tile & 3;
        float w1r[25];
        #pragma unroll
        for (int q = 0; q < 6; ++q) {
            float4 v4 = *(const float4*)&S.f.c1wsP[c * 28 + q * 4];
            w1r[q * 4 + 0] = v4.x; w1r[q * 4 + 1] = v4.y;
            w1r[q * 4 + 2] = v4.z; w1r[q * 4 + 3] = v4.w;
        }
        w1r[24] = S.f.c1wsP[c * 28 + 24];
        float bias1 = c1b[c];
        float win[5][10];
        float pacc[3][3];
        #pragma unroll
        for (int i = 0; i < 3; ++i)
            #pragma unroll
            for (int j = 0; j < 3; ++j) pacc[i][j] = 0.f;
        int r0 = 6 * tr, col0 = 6 * tc;
        #pragma unroll
        for (int cr = 0; cr < 6; ++cr) {
            if (cr == 0) {
                #pragma unroll
                for (int rr = 0; rr < 5; ++rr)
                    #pragma unroll
                    for (int m = 0; m < 5; ++m) {
                        float2 v = *(const float2*)&S.f.xs[(r0 + rr) * 28 + col0 + 2 * m];
                        win[rr][2 * m] = v.x; win[rr][2 * m + 1] = v.y;
                    }
            } else {
                int dstr = (cr + 4) % 5;
                #pragma unroll
                for (int m = 0; m < 5; ++m) {
                    float2 v = *(const float2*)&S.f.xs[(r0 + cr + 4) * 28 + col0 + 2 * m];
                    win[dstr][2 * m] = v.x; win[dstr][2 * m + 1] = v.y;
                }
            }
            #pragma unroll
            for (int oc = 0; oc < 6; ++oc) {
                float s = bias1;
                #pragma unroll
                for (int u = 0; u < 5; ++u)
                    #pragma unroll
                    for (int v = 0; v < 5; ++v)
                        s += win[(cr + u) % 5][oc + v] * w1r[u * 5 + v];
                s = fmaxf(s, 0.f);
                pacc[cr >> 1][oc >> 1] = fmaxf(pacc[cr >> 1][oc >> 1], s);
            }
        }
        #pragma unroll
        for (int i = 0; i < 3; ++i)
            #pragma unroll
            for (int j = 0; j < 3; ++j) {
                int pos = (3 * tr + i) * 12 + (3 * tc + j);
                float v = pacc[i][j];
                _Float16 vh = (_Float16)v;
                S.f.pclh[pos * PCL_S + c] = vh;
                S.f.pcll[pos * PCL_S + c] = (_Float16)(v - (float)vh);
            }
    }
    __syncthreads();

    // conv2 MFMA: wave fixed nt (B frags in regs), mt strided
    float part[5] = {0, 0, 0, 0, 0};
    int lane = t & 63, wv = t >> 6;
    int quad = lane >> 4, l16 = lane & 15;
    int quadh = quad >> 1, quadl = quad & 1;
    const int offA[5] = {0, 2, 13, 24, 26};
    const int offB[5] = {1, 12, 14, 25, 0};
    {
        int nt = wv & 1;
        int co = nt * 16 + l16;
        f16x8 bh[5], bl[5];
        #pragma unroll
        for (int kc = 0; kc < 5; ++kc) {
            bh[kc] = *(const f16x8*)&S.f.b2h[co * 160 + kc * 32 + quad * 8];
            bl[kc] = *(const f16x8*)&S.f.b2l[co * 160 + kc * 32 + quad * 8];
        }
        float bco = c2b[co];
        for (int mt = wv >> 1; mt < 7; mt += 2) {
            int o_a = mt * 16 + l16;
            int o_cl = o_a < 100 ? o_a : 99;
            int pb = (o_cl / 10) * 12 + (o_cl % 10);
            f32x4 acc = (f32x4){0.f, 0.f, 0.f, 0.f};
            #pragma unroll
            for (int kc = 0; kc < 5; ++kc) {
                int off = quadh ? offB[kc] : offA[kc];
                f16x8 ah = *(const f16x8*)&S.f.pclh[(pb + off) * PCL_S + quadl * 8];
                f16x8 al = *(const f16x8*)&S.f.pcll[(pb + off) * PCL_S + quadl * 8];
                acc = __builtin_amdgcn_mfma_f32_16x16x32_f16(ah, bh[kc], acc, 0, 0, 0);
                acc = __builtin_amdgcn_mfma_f32_16x16x32_f16(ah, bl[kc], acc, 0, 0, 0);
                acc = __builtin_amdgcn_mfma_f32_16x16x32_f16(al, bh[kc], acc, 0, 0, 0);
            }
            if (mt < 6 || quad == 0) {
                int o0 = mt * 16 + quad * 4;
                f16x4 st;
                #pragma unroll
                for (int r = 0; r < 4; ++r) {
                    float hv = fmaxf(acc[r] + bco, 0.f);
                    st[r] = (_Float16)hv;
                    #pragma unroll
                    for (int e = 0; e < 5; ++e)
                        part[e] += hv * gwC[e * 3200 + (o0 + r) * 32 + co];
                }
                *(f16x4*)&h16[(size_t)b * D_IN + co * 100 + o0] = st;
            }
        }
    }

    // gate reduce: softmax, top-3 renormalized
    #pragma unroll
    for (int e = 0; e < 5; ++e) {
        float v = part[e];
        for (int off = 32; off > 0; off >>= 1) v += __shfl_down(v, off, 64);
        if (lane == 0) S.f.red[wv * 8 + e] = v;
    }
    __syncthreads();
    if (t == 0) {
        float lg[5], p[5];
        float mx = -1e30f;
        for (int e = 0; e < 5; ++e) {
            lg[e] = S.f.red[e] + S.f.red[8 + e] + S.f.red[16 + e] + S.f.red[24 + e] + gb[e];
            mx = fmaxf(mx, lg[e]);
        }
        float sum = 0.f;
        for (int e = 0; e < 5; ++e) { p[e] = expf(lg[e] - mx); sum += p[e]; }
        for (int e = 0; e < 5; ++e) p[e] /= sum;
        bool used[5] = {false, false, false, false, false};
        float out5[5] = {0, 0, 0, 0, 0};
        int ti[3]; float tv[3]; float tsum = 0.f;
        for (int jj = 0; jj < 3; ++jj) {
            int best = 0; float bv = -1.f;
            for (int e = 0; e < 5; ++e)
                if (!used[e] && p[e] > bv) { bv = p[e]; best = e; }
            used[best] = true; ti[jj] = best; tv[jj] = bv; tsum += bv;
        }
        for (int jj = 0; jj < 3; ++jj) out5[ti[jj]] = tv[jj] / tsum;
        for (int e = 0; e < 5; ++e) wfull[b * 5 + e] = out5[e];
    }
}

// ---------------- kernel 1b: token compaction — wave-aggregated (640 atomics total)
__global__ __launch_bounds__(256) void k_compact(
    const float* __restrict__ wfull, int* __restrict__ cnt, int* __restrict__ lists)
{
    int tok = blockIdx.x * 256 + threadIdx.x;
    int lane = threadIdx.x & 63;
    float w[5];
    #pragma unroll
    for (int e = 0; e < 5; ++e) w[e] = wfull[(size_t)tok * 5 + e];
    #pragma unroll
    for (int e = 0; e < 5; ++e) {
        bool sel = w[e] > 0.f;
        unsigned long long mask = __ballot(sel);
        int leader = __ffsll((long long)mask) - 1;
        int base = 0;
        if (lane == leader) base = atomicAdd(&cnt[e], __popcll(mask));
        base = __shfl(base, leader, 64);
        if (sel) {
            int pos = base + __popcll(mask & ((1ull << lane) - 1ull));
            lists[e * NB + pos] = tok;
        }
    }
}

// ---------------- kernel 2: experts on compacted lists, 64-row M-tiles, BK=64 per
// barrier pair — the measured optimum (R10/R11); 32-row (R12), BK=128 (R13),
// 128-row (R5), dense (R3) all lose. Epilogue: in-block head GEMM -> atomic logits.
#define H1S 136
union SLds {
    struct { _Float16 As0[2048]; _Float16 As1[2048];
             _Float16 Bs0[4096]; _Float16 Bs1[4096]; } p1;   // 24 KB staging
    _Float16 e2ws[128 * H1S];                                // 34.8 KB e2 weights
    float smws[1280];                                        // 5 KB head weights (phase 3)
};

__global__ __launch_bounds__(256, 3) void k_e1e2(
    const _Float16* __restrict__ h16, const _Float16* __restrict__ wT,
    const _Float16* __restrict__ e2T,
    const float* __restrict__ e1b, const float* __restrict__ e2b,
    const float* __restrict__ smw,
    const float* __restrict__ wfull, const int* __restrict__ cnt,
    const int* __restrict__ lists, float* __restrict__ logits)
{
    __shared__ SLds u;
    __shared__ __align__(16) _Float16 h1s[64 * H1S];
    __shared__ float wfl[64];
    __shared__ int rows[64];
    int bid = blockIdx.x;
    int e = bid >> 7;            // expert-major: one B matrix hot per L2 at a time
    int mt = bid & 127;
    int cnt_e = cnt[e];
    int m0 = mt * 64;
    if (m0 >= cnt_e) return;     // inactive tile, uniform exit
    int t = threadIdx.x;
    int lane = t & 63, wv = t >> 6;
    int waveM = wv >> 1, waveN = wv & 1;
    int quad = lane >> 4, l16 = lane & 15;
    if (t < 64) {
        int r = m0 + t;
        int row = (r < cnt_e) ? lists[e * NB + r] : lists[e * NB];  // dup row for tail
        rows[t] = row;
        wfl[t] = (r < cnt_e) ? wfull[(size_t)row * 5 + e] : 0.f;    // tail w=0
    }
    __syncthreads();

    const _Float16* bbase = wT + (size_t)e * (D_H * D_IN);
    int srow = t >> 2;
    int scol = (t & 3) * 8;
    const _Float16* aptr = h16 + (size_t)rows[srow] * D_IN + scol;
    const _Float16* bptr0 = bbase + (size_t)srow * D_IN + scol;
    const _Float16* bptr1 = bbase + (size_t)(64 + srow) * D_IN + scol;
    f32x4 acc[2][4];
    #pragma unroll
    for (int i = 0; i < 2; ++i)
        #pragma unroll
        for (int j = 0; j < 4; ++j) acc[i][j] = (f32x4){0.f, 0.f, 0.f, 0.f};

    for (int k0 = 0; k0 < D_IN; k0 += 64) {
        gload16(aptr + k0,        u.p1.As0 + wv * 512);
        gload16(aptr + k0 + 32,   u.p1.As1 + wv * 512);
        gload16(bptr0 + k0,       u.p1.Bs0 + wv * 512);
        gload16(bptr0 + k0 + 32,  u.p1.Bs1 + wv * 512);
        gload16(bptr1 + k0,       u.p1.Bs0 + 2048 + wv * 512);
        gload16(bptr1 + k0 + 32,  u.p1.Bs1 + 2048 + wv * 512);
        __syncthreads();
        #pragma unroll
        for (int ch = 0; ch < 2; ++ch) {
            const _Float16* Ab = ch ? u.p1.As1 : u.p1.As0;
            const _Float16* Bb = ch ? u.p1.Bs1 : u.p1.Bs0;
            f16x8 af[2], bf[4];
            #pragma unroll
            for (int ms = 0; ms < 2; ++ms)
                af[ms] = *(const f16x8*)&Ab[(waveM * 32 + ms * 16 + l16) * 32 + quad * 8];
            #pragma unroll
            for (int ns = 0; ns < 4; ++ns)
                bf[ns] = *(const f16x8*)&Bb[(waveN * 64 + ns * 16 + l16) * 32 + quad * 8];
            #pragma unroll
            for (int ms = 0; ms < 2; ++ms)
                #pragma unroll
                for (int ns = 0; ns < 4; ++ns)
                    acc[ms][ns] = __builtin_amdgcn_mfma_f32_16x16x32_f16(af[ms], bf[ns], acc[ms][ns], 0, 0, 0);
        }
        __syncthreads();
    }

    // h1 = tanh(acc + b1) -> h1s
    #pragma unroll
    for (int ms = 0; ms < 2; ++ms) {
        int rbase = waveM * 32 + ms * 16 + quad * 4;
        #pragma unroll
        for (int ns = 0; ns < 4; ++ns) {
            int n = waveN * 64 + ns * 16 + l16;
            float bias = e1b[e * D_H + n];
            #pragma unroll
            for (int r = 0; r < 4; ++r)
                h1s[(rbase + r) * H1S + n] = (_Float16)tanhf(acc[ms][ns][r] + bias);
        }
    }
    __syncthreads();   // h1s visible; staging dead -> reuse as e2ws

    {
        int rr = t >> 1, cc = (t & 1) * 64;
        const _Float16* src = e2T + (size_t)e * (D_H * D_H) + (size_t)rr * D_H + cc;
        #pragma unroll
        for (int i = 0; i < 8; ++i)
            *(uint4*)&u.e2ws[rr * H1S + cc + i * 8] = *(const uint4*)(src + i * 8);
    }
    __syncthreads();

    f32x4 acc2[2][4];
    #pragma unroll
    for (int i = 0; i < 2; ++i)
        #pragma unroll
        for (int j = 0; j < 4; ++j) acc2[i][j] = (f32x4){0.f, 0.f, 0.f, 0.f};
    #pragma unroll
    for (int kc = 0; kc < 4; ++kc) {
        f16x8 a2[2], b2[4];
        #pragma unroll
        for (int ms = 0; ms < 2; ++ms)
            a2[ms] = *(const f16x8*)&h1s[(waveM * 32 + ms * 16 + l16) * H1S + kc * 32 + quad * 8];
        #pragma unroll
        for (int ns = 0; ns < 4; ++ns)
            b2[ns] = *(const f16x8*)&u.e2ws[(waveN * 64 + ns * 16 + l16) * H1S + kc * 32 + quad * 8];
        #pragma unroll
        for (int ms = 0; ms < 2; ++ms)
            #pragma unroll
            for (int ns = 0; ns < 4; ++ns)
                acc2[ms][ns] = __builtin_amdgcn_mfma_f32_16x16x32_f16(a2[ms], b2[ns], acc2[ms][ns], 0, 0, 0);
    }
    __syncthreads();   // all h1s/e2ws reads done -> safe to overwrite both

    // wh2 = w * tanh(acc2 + b2) -> h1s (f16); stage smw -> u.smws
    for (int i = t; i < 1280; i += 256) u.smws[i] = smw[i];
    #pragma unroll
    for (int ms = 0; ms < 2; ++ms) {
        int rbase = waveM * 32 + ms * 16 + quad * 4;
        #pragma unroll
        for (int ns = 0; ns < 4; ++ns) {
            int n = waveN * 64 + ns * 16 + l16;
            float bias = e2b[e * D_H + n];
            #pragma unroll
            for (int r = 0; r < 4; ++r) {
                int lrow = rbase + r;
                h1s[lrow * H1S + n] = (_Float16)(wfl[lrow] * tanhf(acc2[ms][ns][r] + bias));
            }
        }
    }
    __syncthreads();

    // in-block head GEMM: partial_logits[64][10] = wh2 @ smw; atomic combine
    for (int i = t; i < 640; i += 256) {
        int row = i / 10, c = i - (i / 10) * 10;
        float s = 0.f;
        #pragma unroll 8
        for (int k = 0; k < 128; ++k)
            s += (float)h1s[row * H1S + k] * u.smws[k * 10 + c];
        unsafeAtomicAdd(&logits[(size_t)rows[row] * 10 + c], s);
    }
}

// ---------------- kernel 3: softmax over logits (+smb) -> out
__global__ __launch_bounds__(256) void k_smax(
    const float* __restrict__ logits, const float* __restrict__ smb,
    float* __restrict__ out)
{
    int r = blockIdx.x * 256 + threadIdx.x;
    float lg[10];
    float mx = -1e30f;
    #pragma unroll
    for (int c = 0; c < 10; ++c) {
        lg[c] = logits[(size_t)r * 10 + c] + smb[c];
        mx = fmaxf(mx, lg[c]);
    }
    float s = 0.f;
    #pragma unroll
    for (int c = 0; c < 10; ++c) { lg[c] = expf(lg[c] - mx); s += lg[c]; }
    float inv = 1.f / s;
    #pragma unroll
    for (int c = 0; c < 10; ++c) out[(size_t)r * 10 + c] = lg[c] * inv;
}

extern "C" void kernel_launch(void* const* d_in, const int* in_sizes, int n_in,
                              void* d_out, int out_size, void* d_ws, size_t ws_size,
                              hipStream_t stream)
{
    const float* x   = (const float*)d_in[0];
    const float* c1w = (const float*)d_in[1];
    const float* c1b = (const float*)d_in[2];
    const float* c2w = (const float*)d_in[3];
    const float* c2b = (const float*)d_in[4];
    const float* gw  = (const float*)d_in[5];
    const float* gb  = (const float*)d_in[6];
    const float* e1w = (const float*)d_in[7];
    const float* e1b = (const float*)d_in[8];
    const float* e2w = (const float*)d_in[9];
    const float* e2b = (const float*)d_in[10];
    const float* smw = (const float*)d_in[11];
    const float* smb = (const float*)d_in[12];
    float* out = (float*)d_out;

    char* ws = (char*)d_ws;
    size_t off = 0;
    auto alloc = [&](size_t bytes) {
        void* p = ws + off;
        off += (bytes + 255) & ~(size_t)255;
        return p;
    };
    _Float16* h16 = (_Float16*)alloc((size_t)NB * D_IN * 2);          // 52.4 MB
    _Float16* wT  = (_Float16*)alloc((size_t)NE * D_H * D_IN * 2);    // 4.1 MB
    _Float16* e2T = (_Float16*)alloc((size_t)NE * D_H * D_H * 2);     // 0.16 MB
    float* wfull  = (float*)alloc((size_t)NB * NE * 4);               // 0.16 MB
    float* logits = (float*)alloc((size_t)NB * 10 * 4);               // 0.33 MB
    float* gwC    = (float*)alloc((size_t)NE * D_IN * 4);             // 64 KB
    int* cnt      = (int*)alloc(NE * 4);
    int* lists    = (int*)alloc((size_t)NE * NB * 4);                 // 160 KB

    hipMemsetAsync(logits, 0, (size_t)NB * 10 * 4, stream);
    k_gwprep<<<dim3(63), 256, 0, stream>>>(gw, gwC, cnt);
    k_feat<<<dim3(520 + NB), 256, 0, stream>>>(x, c1w, c1b, c2w, c2b, gwC, gb,
                                               e1w, wT, e2w, e2T, h16, wfull);
    k_compact<<<dim3(NB / 256), 256, 0, stream>>>(wfull, cnt, lists);
    k_e1e2<<<dim3(128 * NE), 256, 0, stream>>>(h16, wT, e2T, e1b, e2b, smw,
                                               wfull, cnt, lists, logits);
    k_smax<<<dim3(NB / 256), 256, 0, stream>>>(logits, smb, out);
}

// Round 15
// 308.618 us; speedup vs baseline: 1.3310x; 1.0103x over previous
//
#include <hip/hip_runtime.h>
#include <hip/hip_bf16.h>
#include <hip/hip_fp16.h>

#define NB 8192
#define D_IN 3200
#define D_H 128
#define NE 5

typedef _Float16 f16x8 __attribute__((ext_vector_type(8)));
typedef _Float16 f16x4 __attribute__((ext_vector_type(4)));
typedef float f32x4 __attribute__((ext_vector_type(4)));

// async global->LDS, 16B per lane; global addr may be per-lane, LDS base wave-uniform
__device__ __forceinline__ void gload16(const _Float16* g, _Float16* l) {
    __builtin_amdgcn_global_load_lds(
        (const __attribute__((address_space(1))) void*)g,
        (__attribute__((address_space(3))) void*)l, 16, 0, 0);
}

// ---------------- kernel 0: gwC transpose + cnt zero (must precede k_feat: k_feat reads gwC)
__global__ __launch_bounds__(256) void k_gwprep(const float* __restrict__ gw,
                                                float* __restrict__ gwC,
                                                int* __restrict__ cnt) {
    int i = blockIdx.x * 256 + threadIdx.x;
    if (i < 16000) {
        int e = i / 3200, rem = i - e * 3200;
        int o = rem >> 5, co = rem & 31;
        gwC[i] = gw[(co * 100 + o) * 5 + e];
    }
    if (blockIdx.x == 0 && threadIdx.x < NE) cnt[threadIdx.x] = 0;
}

// ---------------- kernel 1: blocks 0-519 = wT/e2T transpose prep; blocks 520+ = conv path.
#define PCL_S 24
__global__ __launch_bounds__(256, 3) void k_feat(
    const float* __restrict__ x, const float* __restrict__ c1w, const float* __restrict__ c1b,
    const float* __restrict__ c2w, const float* __restrict__ c2b,
    const float* __restrict__ gwC, const float* __restrict__ gb,
    const float* __restrict__ e1w, _Float16* __restrict__ wT,
    const float* __restrict__ e2w, _Float16* __restrict__ e2T,
    _Float16* __restrict__ h16, float* __restrict__ wfull)
{
    __shared__ union {
        struct {
            __align__(16) float xs[784];
            __align__(16) float c1wsP[448];
            __align__(16) _Float16 b2h[5120];
            __align__(16) _Float16 b2l[5120];
            __align__(16) _Float16 pclh[144 * PCL_S];
            __align__(16) _Float16 pcll[144 * PCL_S];
            float red[32];
        } f;
        float tile[64 * 65];   // prep transpose scratch (16.6 KB, overlaid)
    } S;
    int bid = blockIdx.x;
    int t = threadIdx.x;

    if (bid < 520) {               // ---- prep path
        if (bid < 500) {           // e1_w [5][3200][128] -> f16 T [5][128][3200]
            int e = bid / 100, rem = bid - e * 100;
            int k0 = (rem >> 1) * 64, n0 = (rem & 1) * 64;
            const float* src = e1w + (size_t)e * D_IN * D_H;
            _Float16* dst = wT + (size_t)e * D_H * D_IN;
            for (int i = 0; i < 16; ++i) {
                int idx = t + i * 256;
                int kr = idx >> 6, nc = idx & 63;
                S.tile[kr * 65 + nc] = src[(size_t)(k0 + kr) * D_H + n0 + nc];
            }
            __syncthreads();
            for (int i = 0; i < 16; ++i) {
                int idx = t + i * 256;
                int nr = idx >> 6, kc = idx & 63;
                dst[(size_t)(n0 + nr) * D_IN + k0 + kc] = (_Float16)S.tile[kc * 65 + nr];
            }
        } else {                   // e2_w [5][128][128] -> f16 T (n,k)
            int idx2 = bid - 500;
            int e = idx2 >> 2, rem = idx2 & 3;
            int k0 = (rem >> 1) * 64, n0 = (rem & 1) * 64;
            const float* src = e2w + (size_t)e * D_H * D_H;
            _Float16* dst = e2T + (size_t)e * D_H * D_H;
            for (int i = 0; i < 16; ++i) {
                int idx = t + i * 256;
                int kr = idx >> 6, nc = idx & 63;
                S.tile[kr * 65 + nc] = src[(size_t)(k0 + kr) * D_H + n0 + nc];
            }
            __syncthreads();
            for (int i = 0; i < 16; ++i) {
                int idx = t + i * 256;
                int nr = idx >> 6, kc = idx & 63;
                dst[(size_t)(n0 + nr) * D_H + k0 + kc] = (_Float16)S.tile[kc * 65 + nr];
            }
        }
        return;
    }

    int b = bid - 520;             // ---- conv path (proven structure, frozen)
    for (int i = t; i < 784; i += 256) S.f.xs[i] = x[(size_t)b * 784 + i];
    for (int i = t; i < 400; i += 256) {
        int c = i / 25, q = i - c * 25;
        S.f.c1wsP[c * 28 + q] = c1w[i];
    }
    for (int i = t; i < 5120; i += 256) {
        int co = i / 160, k = i - co * 160;
        int s = k >> 4, ci = k & 15;
        float v = (s == 9) ? 0.f : c2w[(co * 16 + ci) * 9 + s];
        _Float16 vh = (_Float16)v;
        S.f.b2h[i] = vh;
        S.f.b2l[i] = (_Float16)(v - (float)vh);
    }
    __syncthreads();

    // conv1 + 2x2 maxpool -> pcl channel-last (hi/lo f16)
    {
        int c = t >> 4;
        int tile = t & 15;
        int tr = tile >> 2, tc = tile & 3;
        float w1r[25];
        #pragma unroll
        for (int q = 0; q < 6; ++q) {
            float4 v4 = *(const float4*)&S.f.c1wsP[c * 28 + q * 4];
            w1r[q * 4 + 0] = v4.x; w1r[q * 4 + 1] = v4.y;
            w1r[q * 4 + 2] = v4.z; w1r[q * 4 + 3] = v4.w;
        }
        w1r[24] = S.f.c1wsP[c * 28 + 24];
        float bias1 = c1b[c];
        float win[5][10];
        float pacc[3][3];
        #pragma unroll
        for (int i = 0; i < 3; ++i)
            #pragma unroll
            for (int j = 0; j < 3; ++j) pacc[i][j] = 0.f;
        int r0 = 6 * tr, col0 = 6 * tc;
        #pragma unroll
        for (int cr = 0; cr < 6; ++cr) {
            if (cr == 0) {
                #pragma unroll
                for (int rr = 0; rr < 5; ++rr)
                    #pragma unroll
                    for (int m = 0; m < 5; ++m) {
                        float2 v = *(const float2*)&S.f.xs[(r0 + rr) * 28 + col0 + 2 * m];
                        win[rr][2 * m] = v.x; win[rr][2 * m + 1] = v.y;
                    }
            } else {
                int dstr = (cr + 4) % 5;
                #pragma unroll
                for (int m = 0; m < 5; ++m) {
                    float2 v = *(const float2*)&S.f.xs[(r0 + cr + 4) * 28 + col0 + 2 * m];
                    win[dstr][2 * m] = v.x; win[dstr][2 * m + 1] = v.y;
                }
            }
            #pragma unroll
            for (int oc = 0; oc < 6; ++oc) {
                float s = bias1;
                #pragma unroll
                for (int u = 0; u < 5; ++u)
                    #pragma unroll
                    for (int v = 0; v < 5; ++v)
                        s += win[(cr + u) % 5][oc + v] * w1r[u * 5 + v];
                s = fmaxf(s, 0.f);
                pacc[cr >> 1][oc >> 1] = fmaxf(pacc[cr >> 1][oc >> 1], s);
            }
        }
        #pragma unroll
        for (int i = 0; i < 3; ++i)
            #pragma unroll
            for (int j = 0; j < 3; ++j) {
                int pos = (3 * tr + i) * 12 + (3 * tc + j);
                float v = pacc[i][j];
                _Float16 vh = (_Float16)v;
                S.f.pclh[pos * PCL_S + c] = vh;
                S.f.pcll[pos * PCL_S + c] = (_Float16)(v - (float)vh);
            }
    }
    __syncthreads();

    // conv2 MFMA: wave fixed nt (B frags in regs), mt strided
    float part[5] = {0, 0, 0, 0, 0};
    int lane = t & 63, wv = t >> 6;
    int quad = lane >> 4, l16 = lane & 15;
    int quadh = quad >> 1, quadl = quad & 1;
    const int offA[5] = {0, 2, 13, 24, 26};
    const int offB[5] = {1, 12, 14, 25, 0};
    {
        int nt = wv & 1;
        int co = nt * 16 + l16;
        f16x8 bh[5], bl[5];
        #pragma unroll
        for (int kc = 0; kc < 5; ++kc) {
            bh[kc] = *(const f16x8*)&S.f.b2h[co * 160 + kc * 32 + quad * 8];
            bl[kc] = *(const f16x8*)&S.f.b2l[co * 160 + kc * 32 + quad * 8];
        }
        float bco = c2b[co];
        for (int mt = wv >> 1; mt < 7; mt += 2) {
            int o_a = mt * 16 + l16;
            int o_cl = o_a < 100 ? o_a : 99;
            int pb = (o_cl / 10) * 12 + (o_cl % 10);
            f32x4 acc = (f32x4){0.f, 0.f, 0.f, 0.f};
            #pragma unroll
            for (int kc = 0; kc < 5; ++kc) {
                int off = quadh ? offB[kc] : offA[kc];
                f16x8 ah = *(const f16x8*)&S.f.pclh[(pb + off) * PCL_S + quadl * 8];
                f16x8 al = *(const f16x8*)&S.f.pcll[(pb + off) * PCL_S + quadl * 8];
                acc = __builtin_amdgcn_mfma_f32_16x16x32_f16(ah, bh[kc], acc, 0, 0, 0);
                acc = __builtin_amdgcn_mfma_f32_16x16x32_f16(ah, bl[kc], acc, 0, 0, 0);
                acc = __builtin_amdgcn_mfma_f32_16x16x32_f16(al, bh[kc], acc, 0, 0, 0);
            }
            if (mt < 6 || quad == 0) {
                int o0 = mt * 16 + quad * 4;
                f16x4 st;
                #pragma unroll
                for (int r = 0; r < 4; ++r) {
                    float hv = fmaxf(acc[r] + bco, 0.f);
                    st[r] = (_Float16)hv;
                    #pragma unroll
                    for (int e = 0; e < 5; ++e)
                        part[e] += hv * gwC[e * 3200 + (o0 + r) * 32 + co];
                }
                *(f16x4*)&h16[(size_t)b * D_IN + co * 100 + o0] = st;
            }
        }
    }

    // gate reduce: softmax, top-3 renormalized
    #pragma unroll
    for (int e = 0; e < 5; ++e) {
        float v = part[e];
        for (int off = 32; off > 0; off >>= 1) v += __shfl_down(v, off, 64);
        if (lane == 0) S.f.red[wv * 8 + e] = v;
    }
    __syncthreads();
    if (t == 0) {
        float lg[5], p[5];
        float mx = -1e30f;
        for (int e = 0; e < 5; ++e) {
            lg[e] = S.f.red[e] + S.f.red[8 + e] + S.f.red[16 + e] + S.f.red[24 + e] + gb[e];
            mx = fmaxf(mx, lg[e]);
        }
        float sum = 0.f;
        for (int e = 0; e < 5; ++e) { p[e] = expf(lg[e] - mx); sum += p[e]; }
        for (int e = 0; e < 5; ++e) p[e] /= sum;
        bool used[5] = {false, false, false, false, false};
        float out5[5] = {0, 0, 0, 0, 0};
        int ti[3]; float tv[3]; float tsum = 0.f;
        for (int jj = 0; jj < 3; ++jj) {
            int best = 0; float bv = -1.f;
            for (int e = 0; e < 5; ++e)
                if (!used[e] && p[e] > bv) { bv = p[e]; best = e; }
            used[best] = true; ti[jj] = best; tv[jj] = bv; tsum += bv;
        }
        for (int jj = 0; jj < 3; ++jj) out5[ti[jj]] = tv[jj] / tsum;
        for (int e = 0; e < 5; ++e) wfull[b * 5 + e] = out5[e];
    }
}

// ---------------- kernel 1b: token compaction — wave-aggregated (640 atomics total)
__global__ __launch_bounds__(256) void k_compact(
    const float* __restrict__ wfull, int* __restrict__ cnt, int* __restrict__ lists)
{
    int tok = blockIdx.x * 256 + threadIdx.x;
    int lane = threadIdx.x & 63;
    float w[5];
    #pragma unroll
    for (int e = 0; e < 5; ++e) w[e] = wfull[(size_t)tok * 5 + e];
    #pragma unroll
    for (int e = 0; e < 5; ++e) {
        bool sel = w[e] > 0.f;
        unsigned long long mask = __ballot(sel);
        int leader = __ffsll((long long)mask) - 1;
        int base = 0;
        if (lane == leader) base = atomicAdd(&cnt[e], __popcll(mask));
        base = __shfl(base, leader, 64);
        if (sel) {
            int pos = base + __popcll(mask & ((1ull << lane) - 1ull));
            lists[e * NB + pos] = tok;
        }
    }
}

// ---------------- kernel 2: experts on compacted lists, 64-row M-tiles, BK=64 per
// barrier pair (measured optimum). Epilogue: MFMA head GEMM (smw^T f16, n padded
// to 16) replaces the scalar 640x128 loop -> atomic logits.
#define H1S 136
union SLds {
    struct { _Float16 As0[2048]; _Float16 As1[2048];
             _Float16 Bs0[4096]; _Float16 Bs1[4096]; } p1;   // 24 KB staging
    _Float16 e2ws[128 * H1S];                                // 34.8 KB e2 weights
    _Float16 smwT[16 * 128];                                 // 4 KB head weights^T (phase 3)
};

__global__ __launch_bounds__(256, 3) void k_e1e2(
    const _Float16* __restrict__ h16, const _Float16* __restrict__ wT,
    const _Float16* __restrict__ e2T,
    const float* __restrict__ e1b, const float* __restrict__ e2b,
    const float* __restrict__ smw,
    const float* __restrict__ wfull, const int* __restrict__ cnt,
    const int* __restrict__ lists, float* __restrict__ logits)
{
    __shared__ SLds u;
    __shared__ __align__(16) _Float16 h1s[64 * H1S];
    __shared__ float wfl[64];
    __shared__ int rows[64];
    int bid = blockIdx.x;
    int e = bid >> 7;            // expert-major: one B matrix hot per L2 at a time
    int mt = bid & 127;
    int cnt_e = cnt[e];
    int m0 = mt * 64;
    if (m0 >= cnt_e) return;     // inactive tile, uniform exit
    int t = threadIdx.x;
    int lane = t & 63, wv = t >> 6;
    int waveM = wv >> 1, waveN = wv & 1;
    int quad = lane >> 4, l16 = lane & 15;
    if (t < 64) {
        int r = m0 + t;
        int row = (r < cnt_e) ? lists[e * NB + r] : lists[e * NB];  // dup row for tail
        rows[t] = row;
        wfl[t] = (r < cnt_e) ? wfull[(size_t)row * 5 + e] : 0.f;    // tail w=0
    }
    __syncthreads();

    const _Float16* bbase = wT + (size_t)e * (D_H * D_IN);
    int srow = t >> 2;
    int scol = (t & 3) * 8;
    const _Float16* aptr = h16 + (size_t)rows[srow] * D_IN + scol;
    const _Float16* bptr0 = bbase + (size_t)srow * D_IN + scol;
    const _Float16* bptr1 = bbase + (size_t)(64 + srow) * D_IN + scol;
    f32x4 acc[2][4];
    #pragma unroll
    for (int i = 0; i < 2; ++i)
        #pragma unroll
        for (int j = 0; j < 4; ++j) acc[i][j] = (f32x4){0.f, 0.f, 0.f, 0.f};

    for (int k0 = 0; k0 < D_IN; k0 += 64) {
        gload16(aptr + k0,        u.p1.As0 + wv * 512);
        gload16(aptr + k0 + 32,   u.p1.As1 + wv * 512);
        gload16(bptr0 + k0,       u.p1.Bs0 + wv * 512);
        gload16(bptr0 + k0 + 32,  u.p1.Bs1 + wv * 512);
        gload16(bptr1 + k0,       u.p1.Bs0 + 2048 + wv * 512);
        gload16(bptr1 + k0 + 32,  u.p1.Bs1 + 2048 + wv * 512);
        __syncthreads();
        #pragma unroll
        for (int ch = 0; ch < 2; ++ch) {
            const _Float16* Ab = ch ? u.p1.As1 : u.p1.As0;
            const _Float16* Bb = ch ? u.p1.Bs1 : u.p1.Bs0;
            f16x8 af[2], bf[4];
            #pragma unroll
            for (int ms = 0; ms < 2; ++ms)
                af[ms] = *(const f16x8*)&Ab[(waveM * 32 + ms * 16 + l16) * 32 + quad * 8];
            #pragma unroll
            for (int ns = 0; ns < 4; ++ns)
                bf[ns] = *(const f16x8*)&Bb[(waveN * 64 + ns * 16 + l16) * 32 + quad * 8];
            #pragma unroll
            for (int ms = 0; ms < 2; ++ms)
                #pragma unroll
                for (int ns = 0; ns < 4; ++ns)
                    acc[ms][ns] = __builtin_amdgcn_mfma_f32_16x16x32_f16(af[ms], bf[ns], acc[ms][ns], 0, 0, 0);
        }
        __syncthreads();
    }

    // h1 = tanh(acc + b1) -> h1s
    #pragma unroll
    for (int ms = 0; ms < 2; ++ms) {
        int rbase = waveM * 32 + ms * 16 + quad * 4;
        #pragma unroll
        for (int ns = 0; ns < 4; ++ns) {
            int n = waveN * 64 + ns * 16 + l16;
            float bias = e1b[e * D_H + n];
            #pragma unroll
            for (int r = 0; r < 4; ++r)
                h1s[(rbase + r) * H1S + n] = (_Float16)tanhf(acc[ms][ns][r] + bias);
        }
    }
    __syncthreads();   // h1s visible; staging dead -> reuse as e2ws

    {
        int rr = t >> 1, cc = (t & 1) * 64;
        const _Float16* src = e2T + (size_t)e * (D_H * D_H) + (size_t)rr * D_H + cc;
        #pragma unroll
        for (int i = 0; i < 8; ++i)
            *(uint4*)&u.e2ws[rr * H1S + cc + i * 8] = *(const uint4*)(src + i * 8);
    }
    __syncthreads();

    f32x4 acc2[2][4];
    #pragma unroll
    for (int i = 0; i < 2; ++i)
        #pragma unroll
        for (int j = 0; j < 4; ++j) acc2[i][j] = (f32x4){0.f, 0.f, 0.f, 0.f};
    #pragma unroll
    for (int kc = 0; kc < 4; ++kc) {
        f16x8 a2[2], b2[4];
        #pragma unroll
        for (int ms = 0; ms < 2; ++ms)
            a2[ms] = *(const f16x8*)&h1s[(waveM * 32 + ms * 16 + l16) * H1S + kc * 32 + quad * 8];
        #pragma unroll
        for (int ns = 0; ns < 4; ++ns)
            b2[ns] = *(const f16x8*)&u.e2ws[(waveN * 64 + ns * 16 + l16) * H1S + kc * 32 + quad * 8];
        #pragma unroll
        for (int ms = 0; ms < 2; ++ms)
            #pragma unroll
            for (int ns = 0; ns < 4; ++ns)
                acc2[ms][ns] = __builtin_amdgcn_mfma_f32_16x16x32_f16(a2[ms], b2[ns], acc2[ms][ns], 0, 0, 0);
    }
    __syncthreads();   // all h1s/e2ws reads done -> safe to overwrite both

    // stage smw^T [16(n, zero-padded)][128(k)] f16 into union; wh2 = w*tanh(acc2+b2) -> h1s
    for (int i = t; i < 2048; i += 256) {
        int n = i >> 7, k = i & 127;
        u.smwT[i] = (_Float16)(n < 10 ? smw[k * 10 + n] : 0.f);
    }
    #pragma unroll
    for (int ms = 0; ms < 2; ++ms) {
        int rbase = waveM * 32 + ms * 16 + quad * 4;
        #pragma unroll
        for (int ns = 0; ns < 4; ++ns) {
            int n = waveN * 64 + ns * 16 + l16;
            float bias = e2b[e * D_H + n];
            #pragma unroll
            for (int r = 0; r < 4; ++r) {
                int lrow = rbase + r;
                h1s[lrow * H1S + n] = (_Float16)(wfl[lrow] * tanhf(acc2[ms][ns][r] + bias));
            }
        }
    }
    __syncthreads();

    // MFMA head: per wave one 16-row m-tile: wh2[16x128] @ smw^T[16x128] -> atomic logits
    {
        f32x4 acc3 = (f32x4){0.f, 0.f, 0.f, 0.f};
        #pragma unroll
        for (int kc = 0; kc < 4; ++kc) {
            f16x8 a3 = *(const f16x8*)&h1s[(wv * 16 + l16) * H1S + kc * 32 + quad * 8];
            f16x8 b3 = *(const f16x8*)&u.smwT[l16 * 128 + kc * 32 + quad * 8];
            acc3 = __builtin_amdgcn_mfma_f32_16x16x32_f16(a3, b3, acc3, 0, 0, 0);
        }
        if (l16 < 10) {     // D: row = quad*4+r, col = l16
            #pragma unroll
            for (int r = 0; r < 4; ++r) {
                int row = wv * 16 + quad * 4 + r;
                unsafeAtomicAdd(&logits[(size_t)rows[row] * 10 + l16], acc3[r]);
            }
        }
    }
}

// ---------------- kernel 3: softmax over logits (+smb) -> out
__global__ __launch_bounds__(256) void k_smax(
    const float* __restrict__ logits, const float* __restrict__ smb,
    float* __restrict__ out)
{
    int r = blockIdx.x * 256 + threadIdx.x;
    float lg[10];
    float mx = -1e30f;
    #pragma unroll
    for (int c = 0; c < 10; ++c) {
        lg[c] = logits[(size_t)r * 10 + c] + smb[c];
        mx = fmaxf(mx, lg[c]);
    }
    float s = 0.f;
    #pragma unroll
    for (int c = 0; c < 10; ++c) { lg[c] = expf(lg[c] - mx); s += lg[c]; }
    float inv = 1.f / s;
    #pragma unroll
    for (int c = 0; c < 10; ++c) out[(size_t)r * 10 + c] = lg[c] * inv;
}

extern "C" void kernel_launch(void* const* d_in, const int* in_sizes, int n_in,
                              void* d_out, int out_size, void* d_ws, size_t ws_size,
                              hipStream_t stream)
{
    const float* x   = (const float*)d_in[0];
    const float* c1w = (const float*)d_in[1];
    const float* c1b = (const float*)d_in[2];
    const float* c2w = (const float*)d_in[3];
    const float* c2b = (const float*)d_in[4];
    const float* gw  = (const float*)d_in[5];
    const float* gb  = (const float*)d_in[6];
    const float* e1w = (const float*)d_in[7];
    const float* e1b = (const float*)d_in[8];
    const float* e2w = (const float*)d_in[9];
    const float* e2b = (const float*)d_in[10];
    const float* smw = (const float*)d_in[11];
    const float* smb = (const float*)d_in[12];
    float* out = (float*)d_out;

    char* ws = (char*)d_ws;
    size_t off = 0;
    auto alloc = [&](size_t bytes) {
        void* p = ws + off;
        off += (bytes + 255) & ~(size_t)255;
        return p;
    };
    _Float16* h16 = (_Float16*)alloc((size_t)NB * D_IN * 2);          // 52.4 MB
    _Float16* wT  = (_Float16*)alloc((size_t)NE * D_H * D_IN * 2);    // 4.1 MB
    _Float16* e2T = (_Float16*)alloc((size_t)NE * D_H * D_H * 2);     // 0.16 MB
    float* wfull  = (float*)alloc((size_t)NB * NE * 4);               // 0.16 MB
    float* logits = (float*)alloc((size_t)NB * 10 * 4);               // 0.33 MB
    float* gwC    = (float*)alloc((size_t)NE * D_IN * 4);             // 64 KB
    int* cnt      = (int*)alloc(NE * 4);
    int* lists    = (int*)alloc((size_t)NE * NB * 4);                 // 160 KB

    hipMemsetAsync(logits, 0, (size_t)NB * 10 * 4, stream);
    k_gwprep<<<dim3(63), 256, 0, stream>>>(gw, gwC, cnt);
    k_feat<<<dim3(520 + NB), 256, 0, stream>>>(x, c1w, c1b, c2w, c2b, gwC, gb,
                                               e1w, wT, e2w, e2T, h16, wfull);
    k_compact<<<dim3(NB / 256), 256, 0, stream>>>(wfull, cnt, lists);
    k_e1e2<<<dim3(128 * NE), 256, 0, stream>>>(h16, wT, e2T, e1b, e2b, smw,
                                               wfull, cnt, lists, logits);
    k_smax<<<dim3(NB / 256), 256, 0, stream>>>(logits, smb, out);
}